// Round 9
// baseline (59.586 us; speedup 1.0000x reference)
//
#include <hip/hip_runtime.h>

// BEV pooling (Lift-Splat-Shoot), plane-contiguous gather. MI355X / gfx950.
//
//   x:    flat (Nprime=473088, C=80) f32
//   geom: flat (Nprime, 3) i32
//   out:  (B, C=80, NZ=16, NX=128, NY=128) f32
//   out[b][c][z][x][y] = sum of x[p][c] over in-bounds points p at (x,y,z).
//
// k0: zero shard counters (8 KB/batch).
// k1: bucket kept points by (b, z, x-half, shard=p&63); entry packs (p,gx,gy)
//     in a u64. Entries stay p-sorted within a shard -> L2-friendly x reads.
// k2: one block per (b, z, c, x-half): accumulate a 64x128 half-plane in
//     32 KB LDS (scattered scalar x reads, random-bank LDS atomics), then
//     store 32 KB FULLY CONTIGUOUS nontemporal float4s. The 80 c-blocks of a
//     z-cohort are consecutive blockIdx -> x rows read once from HBM, then
//     L2/L3 hits. Kills the 512B-chunk strided write pattern of all prior
//     versions (the suspected ~2.3 TB/s effective-BW cap).

#define BNX 128
#define BNY 128
#define BNZ 16
#define BC  80
#define PLANE      (BNX * BNY)            // 16384
#define NSEG_PER_B (BNZ * PLANE)          // 262144
#define NSH   128                         // shards per (b,z): 2 x-halves x 64
#define SCAP  256                         // per-shard capacity (mean ~27)
#define HALF  (PLANE / 2)                 // 8192 floats = 32 KB

typedef float fvec4 __attribute__((ext_vector_type(4)));

// ---- kernel 0: cnt = 0 -----------------------------------------------------
__global__ __launch_bounds__(256) void init_cnt(int* __restrict__ cnt, int n)
{
    int i = blockIdx.x * blockDim.x + threadIdx.x;
    if (i < n) cnt[i] = 0;
}

// ---- kernel 1: bucket points ----------------------------------------------
__global__ __launch_bounds__(256) void fill_buckets(
    const int* __restrict__ geom,
    int* __restrict__ cnt,                       // [B*BNZ*NSH]
    unsigned long long* __restrict__ ebuf,       // [B*BNZ*NSH*SCAP]
    int npoints, int per_b)
{
    int p = blockIdx.x * blockDim.x + threadIdx.x;
    if (p >= npoints) return;

    int gx = geom[p * 3 + 0];
    int gy = geom[p * 3 + 1];
    int gz = geom[p * 3 + 2];
    if ((unsigned)gx >= (unsigned)BNX ||
        (unsigned)gy >= (unsigned)BNY ||
        (unsigned)gz >= (unsigned)BNZ) return;

    int b  = p / per_b;
    int bz = b * BNZ + gz;
    int sh = ((gx >> 6) << 6) | (p & 63);        // x-half | p-shard
    int ci = bz * NSH + sh;
    int pos = atomicAdd(&cnt[ci], 1);
    if (pos < SCAP)
        ebuf[(size_t)ci * SCAP + pos] =
            ((unsigned long long)p << 14) | (unsigned)(gx << 7) | (unsigned)gy;
}

// ---- kernel 2: plane gather ------------------------------------------------
// blockIdx = bz*160 + c*2 + h  (consecutive blocks share the z-cohort's data)
__global__ __launch_bounds__(512) void gather_planes(
    const float* __restrict__ x,
    const int* __restrict__ cnt,
    const unsigned long long* __restrict__ ebuf,
    float* __restrict__ out)
{
    __shared__ float acc[HALF];       // 32 KB: acc[lx*128 + gy]
    __shared__ int   scnt[64];

    const int tid = threadIdx.x;
    const int blk = blockIdx.x;
    const int bz  = blk / (BC * 2);
    const int r   = blk - bz * (BC * 2);
    const int c   = r >> 1;
    const int h   = r & 1;            // x-half

    if (tid < 64) scnt[tid] = cnt[bz * NSH + h * 64 + tid];
    {
        fvec4 z4 = {0.f, 0.f, 0.f, 0.f};
        fvec4* a4 = (fvec4*)acc;
        for (int i = tid; i < HALF / 4; i += 512) a4[i] = z4;
    }
    __syncthreads();

    // process: 32 groups of 16 lanes; group g handles shards g and g+32
    const int g    = tid >> 4;
    const int lane = tid & 15;
    for (int s = g; s < 64; s += 32) {
        int n = scnt[s];
        if (n > SCAP) n = SCAP;
        size_t base = (size_t)(bz * NSH + h * 64 + s) * SCAP;
        for (int i = lane; i < n; i += 16) {
            unsigned long long e = ebuf[base + i];
            int pp = (int)(e >> 14);
            int lx = (int)((e >> 7) & 63);
            int gy = (int)(e & 127);
            atomicAdd(&acc[lx * BNY + gy], x[(size_t)pp * BC + c]);
        }
    }
    __syncthreads();

    // store: 32 KB fully contiguous nontemporal float4 stream
    const int b = bz >> 4, z = bz & 15;
    size_t obase = (((size_t)(b * BC + c)) * BNZ + z) * PLANE + (size_t)h * HALF;
    const fvec4* a4 = (const fvec4*)acc;
    fvec4* o4 = (fvec4*)&out[obase];
    for (int i = tid; i < HALF / 4; i += 512)
        __builtin_nontemporal_store(a4[i], &o4[i]);
}

extern "C" void kernel_launch(void* const* d_in, const int* in_sizes, int n_in,
                              void* d_out, int out_size, void* d_ws, size_t ws_size,
                              hipStream_t stream)
{
    const float* x  = (const float*)d_in[0];
    const int* geom = (const int*)d_in[1];
    float* out      = (float*)d_out;

    const int npoints = in_sizes[0] / BC;                 // 473088
    const int B       = out_size / (BC * NSEG_PER_B);     // 1
    const int per_b   = npoints / (B > 0 ? B : 1);
    const int ncnt    = B * BNZ * NSH;                    // 2048*B

    int* cnt = (int*)d_ws;                                // [ncnt]
    unsigned long long* ebuf =
        (unsigned long long*)(cnt + ((ncnt + 1) & ~1));   // 8B-aligned

    init_cnt<<<(ncnt + 255) / 256, 256, 0, stream>>>(cnt, ncnt);

    fill_buckets<<<(npoints + 255) / 256, 256, 0, stream>>>(
        geom, cnt, ebuf, npoints, per_b);

    gather_planes<<<B * BNZ * BC * 2, 512, 0, stream>>>(x, cnt, ebuf, out);
}